// Round 6
// baseline (1643.669 us; speedup 1.0000x reference)
//
#include <hip/hip_runtime.h>
#include <hip/hip_bf16.h>

typedef __attribute__((ext_vector_type(8))) short short8;
typedef __attribute__((ext_vector_type(4))) float floatx4;

#define Bb 64
#define Ii 48
#define Oo 48
#define Ff 256
#define Hh 256
#define NG 1280      // 5*H
#define KK 512       // 2F (Wx rows) == 2H (Ws rows)
#define CHUNK 80     // packed cols per wg = 5 gates x 16 h
#define NH 16        // h-values per chunk
#define HCHUNKS 16   // 1280/80
#define WORKERS 16   // row-workers; worker w owns rows w, w+16, w+32
#define RING 4       // j-ring depth for S/C state
#define WLDS_STRIDE 520      // 512 + 8 pad
#define WLDS_STRIDE_PRE 264  // 256 + 8 pad

// ---------------- pack / cast kernel ----------------
// Gate-major packing: packed col p = hc*80 + g*16 + hsub <-> orig col
// g*256 + hc*16 + hsub. MFMA output block t == gate t, output col lane == h-sub,
// so the recurrent kernel consumes its accumulators directly (no LDS transpose).
__global__ __launch_bounds__(256) void pack_kernel(
    const float* __restrict__ Wx, const float* __restrict__ Ws,
    const float* __restrict__ x, const float* __restrict__ y,
    __hip_bfloat16* __restrict__ Wxp, __hip_bfloat16* __restrict__ Wsp,
    __hip_bfloat16* __restrict__ xb, __hip_bfloat16* __restrict__ yb) {
  int idx = blockIdx.x * blockDim.x + threadIdx.x;
  int stride = gridDim.x * blockDim.x;
  int total_w = NG * KK;
  for (int t = idx; t < total_w; t += stride) {
    int np = t / KK, k = t % KK;
    int hcp = np / CHUNK;
    int rem = np - hcp * CHUNK;
    int g = rem >> 4;
    int hsub = rem & 15;
    int orig = g * Hh + hcp * NH + hsub;
    Wxp[t] = __float2bfloat16(Wx[k * NG + orig]);
    Wsp[t] = __float2bfloat16(Ws[k * NG + orig]);
  }
  int total_x = Bb * Ii * Ff;
  for (int t = idx; t < total_x; t += stride) {
    int f = t % Ff; int rest = t / Ff; int b = rest % Bb; int i = rest / Bb;
    xb[(i * Bb + b) * Ff + f] = __float2bfloat16(x[(b * Ii + i) * Ff + f]);
    yb[(i * Bb + b) * Ff + f] = __float2bfloat16(y[(b * Oo + i) * Ff + f]);
  }
}

// ---------------- precompute GEMM: Px[i][b][n'], Py[j][b][n'] (packing-agnostic)
__global__ __launch_bounds__(256) void pregemm(
    const __hip_bfloat16* __restrict__ xb, const __hip_bfloat16* __restrict__ yb,
    const __hip_bfloat16* __restrict__ Wxp,
    float* __restrict__ Px, float* __restrict__ Py) {
  __shared__ __hip_bfloat16 Wl[CHUNK * WLDS_STRIDE_PRE];
  int wg = blockIdx.x;
  int isY = wg >= (Ii * HCHUNKS);
  int w = isY ? wg - Ii * HCHUNKS : wg;
  int mblk = w >> 4;
  int hc = w & 15;
  int n0 = hc * CHUNK;
  int koff = isY ? Ff : 0;
  int tid = threadIdx.x;
  for (int idx = tid; idx < CHUNK * (Ff / 8); idx += 256) {
    int cl = idx >> 5;
    int kb = (idx & 31) << 3;
    *(short8*)&Wl[cl * WLDS_STRIDE_PRE + kb] =
        *(const short8*)&Wxp[(n0 + cl) * KK + koff + kb];
  }
  __syncthreads();
  int wave = tid >> 6, lane = tid & 63;
  int lr = lane & 15, q = lane >> 4;
  const __hip_bfloat16* Arow = (isY ? yb : xb) + ((size_t)mblk * Bb + wave * 16 + lr) * Ff;
  floatx4 acc[5];
#pragma unroll
  for (int t = 0; t < 5; t++) acc[t] = (floatx4){0.f, 0.f, 0.f, 0.f};
#pragma unroll
  for (int ks = 0; ks < Ff / 32; ks++) {
    int k = ks * 32 + q * 8;
    short8 a = *(const short8*)(Arow + k);
#pragma unroll
    for (int t = 0; t < 5; t++) {
      short8 bfr = *(const short8*)&Wl[(t * 16 + lr) * WLDS_STRIDE_PRE + k];
      acc[t] = __builtin_amdgcn_mfma_f32_16x16x32_bf16(a, bfr, acc[t], 0, 0, 0);
    }
  }
  float* Pr = (isY ? Py : Px) + (size_t)mblk * Bb * NG + n0;
#pragma unroll
  for (int t = 0; t < 5; t++)
#pragma unroll
    for (int r = 0; r < 4; r++)
      Pr[(wave * 16 + q * 4 + r) * NG + t * 16 + lr] = acc[t][r];
}

// ---------------- coherence helpers (L2-bypassing, no cache-wide fences) ----
__device__ __forceinline__ void wait16(const int* p) {
  while (__hip_atomic_load(p, __ATOMIC_RELAXED, __HIP_MEMORY_SCOPE_AGENT) < HCHUNKS)
    __builtin_amdgcn_s_sleep(1);
}

// 16B bf16 A-fragment via two 8B agent-scope (L1/L2-bypass) loads
__device__ __forceinline__ short8 load8_sc(const __hip_bfloat16* p) {
  const unsigned long long* q = (const unsigned long long*)p;
  union { unsigned long long u[2]; short8 v; } r;
  r.u[0] = __hip_atomic_load(q,     __ATOMIC_RELAXED, __HIP_MEMORY_SCOPE_AGENT);
  r.u[1] = __hip_atomic_load(q + 1, __ATOMIC_RELAXED, __HIP_MEMORY_SCOPE_AGENT);
  return r.v;
}

__device__ __forceinline__ void store_bf16_sc(__hip_bfloat16* p, float f) {
  union { __hip_bfloat16 b; unsigned short u; } cv;
  cv.b = __float2bfloat16(f);
  __hip_atomic_store((unsigned short*)p, cv.u, __ATOMIC_RELAXED, __HIP_MEMORY_SCOPE_AGENT);
}

// ---------------- row-pipelined recurrent kernel ----------------
// PROVEN schedule (r0/r3): 256 wgs = 16 row-workers x 16 hchunks, 1 wg/CU.
// Worker w processes rows w, w+16, w+32, each j=0..47 left-to-right. Per cell,
// waits (now LANE-PARALLEL: lanes 0/1/2 of wave 0 poll the three flags in one
// masked vector loop -> one LLC round instead of three serial rounds):
//   lane0: done[i-1][j]   (vertical data dep: S row above + C above)
//   lane1: done[i][j-1]   (sibling hchunks' S slices of own row)
//   lane2: done[i+1][j-4] (WAR: depth-4 j-ring slot reuse)
// State exchanged via agent-scope loads/stores; Px/Py/Wsp stay L2-resident.
// r6 deltas vs r3 (semantics-preserving latency trims):
//   - lane-parallel flag polling (above)
//   - `out` stores deferred until after the publish (out is never read
//     in-kernel, so it need not be drained before the flag bump)
//   - chv loads moved after the GEMM loop in source order (consumed only at
//     elementwise; shortens the barrier->first-A-load critical section)
__global__ __launch_bounds__(256) void lstm_row(
    const float* __restrict__ Px, const float* __restrict__ Py,
    const float* __restrict__ bias, const __hip_bfloat16* __restrict__ Wsp,
    __hip_bfloat16* __restrict__ Sring, float* __restrict__ Cring,
    const __hip_bfloat16* __restrict__ Szero,
    float* __restrict__ out, int* __restrict__ done) {
  __shared__ __hip_bfloat16 Wl[CHUNK * WLDS_STRIDE];  // 83,200 B (only LDS use)
  int wg = blockIdx.x;
  int worker = wg >> 4;
  int hc = wg & 15;
  int n0 = hc * CHUNK;
  int h0 = hc * NH;
  int tid = threadIdx.x;
  int wave = tid >> 6, lane = tid & 63;
  int lr = lane & 15, q = lane >> 4;
  const int brow = wave * 16 + q * 4;   // elementwise b-rows: brow..brow+3
  const int hme = h0 + lr;              // this thread's h
  const size_t BH = (size_t)Bb * Hh;

  // persistent Ws slice: 80 packed cols x 512 k
  for (int idx = tid; idx < CHUNK * (KK / 8); idx += 256) {
    int cl = idx >> 6;
    int kb = (idx & 63) << 3;
    *(short8*)&Wl[cl * WLDS_STRIDE + kb] = *(const short8*)&Wsp[(n0 + cl) * KK + kb];
  }
  float bv[5];
#pragma unroll
  for (int g = 0; g < 5; g++) bv[g] = bias[g * Hh + hme];

#pragma unroll 1
  for (int rr = 0; rr < 3; rr++) {
    int i = worker + rr * WORKERS;
    // ---- per-row: Px slice -> registers (reused for 48 cells) ----
    float pxv[4][5];
#pragma unroll
    for (int ra = 0; ra < 4; ra++)
#pragma unroll
      for (int g = 0; g < 5; g++)
        pxv[ra][g] = Px[((size_t)i * Bb + (brow + ra)) * NG + n0 + g * 16 + lr];

    float cvreg[4];   // register-carried horizontal C state c(i, j-1)
#pragma unroll
    for (int it = 0; it < 4; it++) cvreg[it] = 0.f;

#pragma unroll 1
    for (int j = 0; j < Oo; j++) {
      // ---- prefetch Py slice (immutable, L2-cacheable) before the waits ----
      const float* PyR = Py + (size_t)j * Bb * NG + n0;
      float pyv[4][5];
#pragma unroll
      for (int ra = 0; ra < 4; ra++)
#pragma unroll
        for (int g = 0; g < 5; g++)
          pyv[ra][g] = PyR[(size_t)(brow + ra) * NG + g * 16 + lr];

      // ---- waits: lanes 0/1/2 of wave 0 poll in parallel, barrier broadcasts
      if (tid < 3) {
        const int* fp = nullptr;
        if (tid == 0) {
          if (i > 0) fp = done + (i - 1) * Oo + j;
        } else if (tid == 1) {
          if (j > 0) fp = done + i * Oo + (j - 1);
        } else {
          if (i + 1 < Ii && j >= RING) fp = done + (i + 1) * Oo + (j - RING);
        }
        if (fp) wait16(fp);
      }
      __syncthreads();   // also covers initial Wl staging (rr==0, j==0)

      // ---- state pointers (depth-4 j-ring) ----
      const __hip_bfloat16* Sv = (i > 0)
          ? Sring + ((size_t)(i - 1) * RING + (j & (RING - 1))) * BH : Szero;
      const __hip_bfloat16* Sh = (j > 0)
          ? Sring + ((size_t)i * RING + ((j - 1) & (RING - 1))) * BH : Szero;
      __hip_bfloat16* Sout = Sring + ((size_t)i * RING + (j & (RING - 1))) * BH;
      float* Cout = Cring + ((size_t)i * RING + (j & (RING - 1))) * BH;

      // ---- GEMM: (64 x 512) @ (512 x 80); A = [S_above | S_left] ----
      const __hip_bfloat16* SvR = Sv + (size_t)(wave * 16 + lr) * Hh;
      const __hip_bfloat16* ShR = Sh + (size_t)(wave * 16 + lr) * Hh;
      floatx4 acc[5];
#pragma unroll
      for (int t = 0; t < 5; t++) acc[t] = (floatx4){0.f, 0.f, 0.f, 0.f};
#pragma unroll
      for (int ks = 0; ks < KK / 32; ks++) {
        int k = ks * 32 + q * 8;
        short8 a = (k < Hh) ? load8_sc(SvR + k) : load8_sc(ShR + (k - Hh));
#pragma unroll
        for (int t = 0; t < 5; t++) {
          short8 bfr = *(const short8*)&Wl[(t * 16 + lr) * WLDS_STRIDE + k];
          acc[t] = __builtin_amdgcn_mfma_f32_16x16x32_bf16(a, bfr, acc[t], 0, 0, 0);
        }
      }

      // ---- C-above loads (agent scope; consumed only below, overlap MFMAs) --
      float chv[4];
      if (i > 0) {
        const float* Chp = Cring + ((size_t)(i - 1) * RING + (j & (RING - 1))) * BH;
#pragma unroll
        for (int ra = 0; ra < 4; ra++)
          chv[ra] = __hip_atomic_load(&Chp[(size_t)(brow + ra) * Hh + hme],
                                      __ATOMIC_RELAXED, __HIP_MEMORY_SCOPE_AGENT);
      } else {
#pragma unroll
        for (int ra = 0; ra < 4; ra++) chv[ra] = 0.f;
      }

      // ---- elementwise LSTM update directly from accumulators ----
      // acc[t][ra] = (gate t, b = brow+ra, h = hme)
      float snv[4];
#pragma unroll
      for (int ra = 0; ra < 4; ra++) {
        int b = brow + ra;
        float pre[5];
#pragma unroll
        for (int g = 0; g < 5; g++)
          pre[g] = acc[g][ra] + pxv[ra][g] + pyv[ra][g] + bv[g];
        float ig = 1.f / (1.f + __expf(-pre[0]));
        float fg = 1.f / (1.f + __expf(-pre[1]));
        float og = 1.f / (1.f + __expf(-pre[2]));
        float lg = 1.f / (1.f + __expf(-pre[3]));
        float gg = 1.f - 2.f / (__expf(2.f * pre[4]) + 1.f);   // tanh
        float cn = fg * (lg * chv[ra] + (1.f - lg) * cvreg[ra]) + ig * gg;
        float tc = 1.f - 2.f / (__expf(2.f * cn) + 1.f);
        float sn = og * tc;
        cvreg[ra] = cn;                      // horizontal C for cell (i, j+1)
        snv[ra] = sn;
        __hip_atomic_store(&Cout[(size_t)b * Hh + hme], cn,
                           __ATOMIC_RELAXED, __HIP_MEMORY_SCOPE_AGENT);
        store_bf16_sc(&Sout[(size_t)b * Hh + hme], sn);
      }
      // ---- publish: drain S/C stores (vmcnt(0) via barrier), bump flag ----
      __syncthreads();
      if (tid == 0) atomicAdd(done + i * Oo + j, 1);
      // ---- out stores AFTER publish (never read in-kernel; overlaps next
      //      cell's poll; drained by the next publish barrier / kernel end) --
#pragma unroll
      for (int ra = 0; ra < 4; ra++)
        out[(((size_t)i * Oo + j) * Bb + (brow + ra)) * Hh + hme] = snv[ra];
    }
  }
}

// ---------------- host ----------------
extern "C" void kernel_launch(void* const* d_in, const int* in_sizes, int n_in,
                              void* d_out, int out_size, void* d_ws, size_t ws_size,
                              hipStream_t stream) {
  const float* x    = (const float*)d_in[0];
  const float* y    = (const float*)d_in[1];
  const float* Wx   = (const float*)d_in[2];
  const float* Ws   = (const float*)d_in[3];
  const float* bias = (const float*)d_in[4];
  float* out = (float*)d_out;

  char* ws = (char*)d_ws;
  size_t off = 0;
  auto alloc = [&](size_t bytes) -> void* {
    void* p = ws + off;
    off += (bytes + 255) & ~(size_t)255;
    return p;
  };
  __hip_bfloat16* Wxp = (__hip_bfloat16*)alloc((size_t)NG * KK * 2);
  __hip_bfloat16* Wsp = (__hip_bfloat16*)alloc((size_t)NG * KK * 2);
  __hip_bfloat16* xb  = (__hip_bfloat16*)alloc((size_t)Ii * Bb * Ff * 2);
  __hip_bfloat16* yb  = (__hip_bfloat16*)alloc((size_t)Oo * Bb * Ff * 2);
  float* Px = (float*)alloc((size_t)Ii * Bb * NG * 4);
  float* Py = (float*)alloc((size_t)Oo * Bb * NG * 4);
  __hip_bfloat16* Sring = (__hip_bfloat16*)alloc((size_t)Ii * RING * Bb * Hh * 2);
  float* Cring = (float*)alloc((size_t)Ii * RING * Bb * Hh * 4);
  char* zbase = ws + off;
  __hip_bfloat16* Szero = (__hip_bfloat16*)alloc((size_t)Bb * Hh * 2);
  int*   done = (int*)alloc((size_t)Ii * Oo * 4);
  size_t zBytes = (size_t)((ws + off) - zbase);

  // only the zero-buffer + flags need zeroing (ring slots are written before
  // any read per the dependency order)
  hipMemsetAsync(zbase, 0, zBytes, stream);

  hipLaunchKernelGGL(pack_kernel, dim3(512), dim3(256), 0, stream,
                     Wx, Ws, x, y, Wxp, Wsp, xb, yb);
  hipLaunchKernelGGL(pregemm, dim3(2 * Ii * HCHUNKS), dim3(256), 0, stream,
                     xb, yb, Wxp, Px, Py);

  void* args[] = {(void*)&Px, (void*)&Py, (void*)&bias, (void*)&Wsp,
                  (void*)&Sring, (void*)&Cring, (void*)&Szero,
                  (void*)&out, (void*)&done};
  hipLaunchCooperativeKernel((void*)lstm_row, dim3(WORKERS * HCHUNKS), dim3(256),
                             args, 0, stream);
}

// Round 7
// 1508.508 us; speedup vs baseline: 1.0896x; 1.0896x over previous
//
#include <hip/hip_runtime.h>
#include <hip/hip_bf16.h>

typedef __attribute__((ext_vector_type(8))) short short8;
typedef __attribute__((ext_vector_type(4))) float floatx4;

#define Bb 64
#define Ii 48
#define Oo 48
#define Ff 256
#define Hh 256
#define NG 1280      // 5*H
#define KK 512       // 2F (Wx rows) == 2H (Ws rows)
#define CHUNK 80     // packed cols per wg = 5 gates x 16 h
#define NH 16        // h-values per chunk
#define HCHUNKS 16   // 1280/80
#define WORKERS 16   // row-workers; worker w owns rows w, w+16, w+32
#define RING 4       // j-ring depth for S/C state
#define WLDS_STRIDE 520      // 512 + 8 pad
#define WLDS_STRIDE_PRE 264  // 256 + 8 pad

// ---------------- pack / cast kernel ----------------
// Gate-major packing: packed col p = hc*80 + g*16 + hsub <-> orig col
// g*256 + hc*16 + hsub. MFMA output block t == gate t, output col lane == h-sub,
// so the recurrent kernel consumes its accumulators directly (no LDS transpose).
__global__ __launch_bounds__(256) void pack_kernel(
    const float* __restrict__ Wx, const float* __restrict__ Ws,
    const float* __restrict__ x, const float* __restrict__ y,
    __hip_bfloat16* __restrict__ Wxp, __hip_bfloat16* __restrict__ Wsp,
    __hip_bfloat16* __restrict__ xb, __hip_bfloat16* __restrict__ yb) {
  int idx = blockIdx.x * blockDim.x + threadIdx.x;
  int stride = gridDim.x * blockDim.x;
  int total_w = NG * KK;
  for (int t = idx; t < total_w; t += stride) {
    int np = t / KK, k = t % KK;
    int hcp = np / CHUNK;
    int rem = np - hcp * CHUNK;
    int g = rem >> 4;
    int hsub = rem & 15;
    int orig = g * Hh + hcp * NH + hsub;
    Wxp[t] = __float2bfloat16(Wx[k * NG + orig]);
    Wsp[t] = __float2bfloat16(Ws[k * NG + orig]);
  }
  int total_x = Bb * Ii * Ff;
  for (int t = idx; t < total_x; t += stride) {
    int f = t % Ff; int rest = t / Ff; int b = rest % Bb; int i = rest / Bb;
    xb[(i * Bb + b) * Ff + f] = __float2bfloat16(x[(b * Ii + i) * Ff + f]);
    yb[(i * Bb + b) * Ff + f] = __float2bfloat16(y[(b * Oo + i) * Ff + f]);
  }
}

// ---------------- precompute GEMM: Px[i][b][n'], Py[j][b][n'] (packing-agnostic)
__global__ __launch_bounds__(256) void pregemm(
    const __hip_bfloat16* __restrict__ xb, const __hip_bfloat16* __restrict__ yb,
    const __hip_bfloat16* __restrict__ Wxp,
    float* __restrict__ Px, float* __restrict__ Py) {
  __shared__ __hip_bfloat16 Wl[CHUNK * WLDS_STRIDE_PRE];
  int wg = blockIdx.x;
  int isY = wg >= (Ii * HCHUNKS);
  int w = isY ? wg - Ii * HCHUNKS : wg;
  int mblk = w >> 4;
  int hc = w & 15;
  int n0 = hc * CHUNK;
  int koff = isY ? Ff : 0;
  int tid = threadIdx.x;
  for (int idx = tid; idx < CHUNK * (Ff / 8); idx += 256) {
    int cl = idx >> 5;
    int kb = (idx & 31) << 3;
    *(short8*)&Wl[cl * WLDS_STRIDE_PRE + kb] =
        *(const short8*)&Wxp[(n0 + cl) * KK + koff + kb];
  }
  __syncthreads();
  int wave = tid >> 6, lane = tid & 63;
  int lr = lane & 15, q = lane >> 4;
  const __hip_bfloat16* Arow = (isY ? yb : xb) + ((size_t)mblk * Bb + wave * 16 + lr) * Ff;
  floatx4 acc[5];
#pragma unroll
  for (int t = 0; t < 5; t++) acc[t] = (floatx4){0.f, 0.f, 0.f, 0.f};
#pragma unroll
  for (int ks = 0; ks < Ff / 32; ks++) {
    int k = ks * 32 + q * 8;
    short8 a = *(const short8*)(Arow + k);
#pragma unroll
    for (int t = 0; t < 5; t++) {
      short8 bfr = *(const short8*)&Wl[(t * 16 + lr) * WLDS_STRIDE_PRE + k];
      acc[t] = __builtin_amdgcn_mfma_f32_16x16x32_bf16(a, bfr, acc[t], 0, 0, 0);
    }
  }
  float* Pr = (isY ? Py : Px) + (size_t)mblk * Bb * NG + n0;
#pragma unroll
  for (int t = 0; t < 5; t++)
#pragma unroll
    for (int r = 0; r < 4; r++)
      Pr[(wave * 16 + q * 4 + r) * NG + t * 16 + lr] = acc[t][r];
}

// ---------------- coherence helpers (L2-bypassing, no cache-wide fences) ----
__device__ __forceinline__ void wait16(const int* p) {
  while (__hip_atomic_load(p, __ATOMIC_RELAXED, __HIP_MEMORY_SCOPE_AGENT) < HCHUNKS)
    __builtin_amdgcn_s_sleep(1);
}

// 16B bf16 A-fragment via two 8B agent-scope (L1/L2-bypass) loads
__device__ __forceinline__ short8 load8_sc(const __hip_bfloat16* p) {
  const unsigned long long* q = (const unsigned long long*)p;
  union { unsigned long long u[2]; short8 v; } r;
  r.u[0] = __hip_atomic_load(q,     __ATOMIC_RELAXED, __HIP_MEMORY_SCOPE_AGENT);
  r.u[1] = __hip_atomic_load(q + 1, __ATOMIC_RELAXED, __HIP_MEMORY_SCOPE_AGENT);
  return r.v;
}

__device__ __forceinline__ void store_bf16_sc(__hip_bfloat16* p, float f) {
  union { __hip_bfloat16 b; unsigned short u; } cv;
  cv.b = __float2bfloat16(f);
  __hip_atomic_store((unsigned short*)p, cv.u, __ATOMIC_RELAXED, __HIP_MEMORY_SCOPE_AGENT);
}

// ---------------- row-pipelined recurrent kernel ----------------
// PROVEN schedule (r0/r3/r6): 256 wgs = 16 row-workers x 16 hchunks, 1 wg/CU.
// Worker w processes rows w, w+16, w+32, each j=0..47 left-to-right. Per cell,
// lane-parallel waits (lanes 0/1/2 of wave 0):
//   lane0: done[i-1][j]   (vertical data dep: S row above + C above)
//   lane1: done[i][j-1]   (sibling hchunks' S slices of own row)
//   lane2: done[i+1][j-4] (WAR: depth-4 j-ring slot reuse)
// State exchanged via agent-scope loads/stores; Px/Py/Wsp stay L2-resident.
// r7 delta vs r6 (load-scheduling only, no sync change): ALL 16 A-fragments
// (32x8B agent-scope loads, 64 VGPRs) are issued UPFRONT, then the MFMA loop
// consumes them from registers. Previously each ks iteration loaded its
// fragment and immediately MFMA'd it -> 16 serial LLC round trips (~3.5 us
// exposed latency per cell). Now: one LLC latency, fully overlapped. chv
// loads issue right behind the A-batch and drain under the MFMAs. 1 wg/CU =
// 1 wave/SIMD -> 512-VGPR budget, so the extra 64 VGPRs cost nothing.
__global__ __launch_bounds__(256) void lstm_row(
    const float* __restrict__ Px, const float* __restrict__ Py,
    const float* __restrict__ bias, const __hip_bfloat16* __restrict__ Wsp,
    __hip_bfloat16* __restrict__ Sring, float* __restrict__ Cring,
    const __hip_bfloat16* __restrict__ Szero,
    float* __restrict__ out, int* __restrict__ done) {
  __shared__ __hip_bfloat16 Wl[CHUNK * WLDS_STRIDE];  // 83,200 B (only LDS use)
  int wg = blockIdx.x;
  int worker = wg >> 4;
  int hc = wg & 15;
  int n0 = hc * CHUNK;
  int h0 = hc * NH;
  int tid = threadIdx.x;
  int wave = tid >> 6, lane = tid & 63;
  int lr = lane & 15, q = lane >> 4;
  const int brow = wave * 16 + q * 4;   // elementwise b-rows: brow..brow+3
  const int hme = h0 + lr;              // this thread's h
  const size_t BH = (size_t)Bb * Hh;

  // persistent Ws slice: 80 packed cols x 512 k
  for (int idx = tid; idx < CHUNK * (KK / 8); idx += 256) {
    int cl = idx >> 6;
    int kb = (idx & 63) << 3;
    *(short8*)&Wl[cl * WLDS_STRIDE + kb] = *(const short8*)&Wsp[(n0 + cl) * KK + kb];
  }
  float bv[5];
#pragma unroll
  for (int g = 0; g < 5; g++) bv[g] = bias[g * Hh + hme];

#pragma unroll 1
  for (int rr = 0; rr < 3; rr++) {
    int i = worker + rr * WORKERS;
    // ---- per-row: Px slice -> registers (reused for 48 cells) ----
    float pxv[4][5];
#pragma unroll
    for (int ra = 0; ra < 4; ra++)
#pragma unroll
      for (int g = 0; g < 5; g++)
        pxv[ra][g] = Px[((size_t)i * Bb + (brow + ra)) * NG + n0 + g * 16 + lr];

    float cvreg[4];   // register-carried horizontal C state c(i, j-1)
#pragma unroll
    for (int it = 0; it < 4; it++) cvreg[it] = 0.f;

#pragma unroll 1
    for (int j = 0; j < Oo; j++) {
      // ---- prefetch Py slice (immutable, L2-cacheable) before the waits ----
      const float* PyR = Py + (size_t)j * Bb * NG + n0;
      float pyv[4][5];
#pragma unroll
      for (int ra = 0; ra < 4; ra++)
#pragma unroll
        for (int g = 0; g < 5; g++)
          pyv[ra][g] = PyR[(size_t)(brow + ra) * NG + g * 16 + lr];

      // ---- waits: lanes 0/1/2 of wave 0 poll in parallel, barrier broadcasts
      if (tid < 3) {
        const int* fp = nullptr;
        if (tid == 0) {
          if (i > 0) fp = done + (i - 1) * Oo + j;
        } else if (tid == 1) {
          if (j > 0) fp = done + i * Oo + (j - 1);
        } else {
          if (i + 1 < Ii && j >= RING) fp = done + (i + 1) * Oo + (j - RING);
        }
        if (fp) wait16(fp);
      }
      __syncthreads();   // also covers initial Wl staging (rr==0, j==0)

      // ---- state pointers (depth-4 j-ring) ----
      const __hip_bfloat16* Sv = (i > 0)
          ? Sring + ((size_t)(i - 1) * RING + (j & (RING - 1))) * BH : Szero;
      const __hip_bfloat16* Sh = (j > 0)
          ? Sring + ((size_t)i * RING + ((j - 1) & (RING - 1))) * BH : Szero;
      __hip_bfloat16* Sout = Sring + ((size_t)i * RING + (j & (RING - 1))) * BH;
      float* Cout = Cring + ((size_t)i * RING + (j & (RING - 1))) * BH;

      // ---- A-operand batch prefetch: 16 fragments (32x8B agent loads) in
      //      flight at once -> one LLC latency instead of 16 serial ----
      const __hip_bfloat16* SvR = Sv + (size_t)(wave * 16 + lr) * Hh;
      const __hip_bfloat16* ShR = Sh + (size_t)(wave * 16 + lr) * Hh;
      short8 av[16];
#pragma unroll
      for (int ks = 0; ks < 8; ks++)
        av[ks] = load8_sc(SvR + ks * 32 + q * 8);
#pragma unroll
      for (int ks = 0; ks < 8; ks++)
        av[8 + ks] = load8_sc(ShR + ks * 32 + q * 8);

      // ---- C-above loads issued behind the A-batch; drain under MFMAs ----
      float chv[4];
      if (i > 0) {
        const float* Chp = Cring + ((size_t)(i - 1) * RING + (j & (RING - 1))) * BH;
#pragma unroll
        for (int ra = 0; ra < 4; ra++)
          chv[ra] = __hip_atomic_load(&Chp[(size_t)(brow + ra) * Hh + hme],
                                      __ATOMIC_RELAXED, __HIP_MEMORY_SCOPE_AGENT);
      } else {
#pragma unroll
        for (int ra = 0; ra < 4; ra++) chv[ra] = 0.f;
      }

      // ---- GEMM: (64 x 512) @ (512 x 80) from registers + LDS B ----
      floatx4 acc[5];
#pragma unroll
      for (int t = 0; t < 5; t++) acc[t] = (floatx4){0.f, 0.f, 0.f, 0.f};
#pragma unroll
      for (int ks = 0; ks < KK / 32; ks++) {
        int k = ks * 32 + q * 8;
#pragma unroll
        for (int t = 0; t < 5; t++) {
          short8 bfr = *(const short8*)&Wl[(t * 16 + lr) * WLDS_STRIDE + k];
          acc[t] = __builtin_amdgcn_mfma_f32_16x16x32_bf16(av[ks], bfr, acc[t], 0, 0, 0);
        }
      }

      // ---- elementwise LSTM update directly from accumulators ----
      // acc[t][ra] = (gate t, b = brow+ra, h = hme)
      float snv[4];
#pragma unroll
      for (int ra = 0; ra < 4; ra++) {
        int b = brow + ra;
        float pre[5];
#pragma unroll
        for (int g = 0; g < 5; g++)
          pre[g] = acc[g][ra] + pxv[ra][g] + pyv[ra][g] + bv[g];
        float ig = 1.f / (1.f + __expf(-pre[0]));
        float fg = 1.f / (1.f + __expf(-pre[1]));
        float og = 1.f / (1.f + __expf(-pre[2]));
        float lg = 1.f / (1.f + __expf(-pre[3]));
        float gg = 1.f - 2.f / (__expf(2.f * pre[4]) + 1.f);   // tanh
        float cn = fg * (lg * chv[ra] + (1.f - lg) * cvreg[ra]) + ig * gg;
        float tc = 1.f - 2.f / (__expf(2.f * cn) + 1.f);
        float sn = og * tc;
        cvreg[ra] = cn;                      // horizontal C for cell (i, j+1)
        snv[ra] = sn;
        __hip_atomic_store(&Cout[(size_t)b * Hh + hme], cn,
                           __ATOMIC_RELAXED, __HIP_MEMORY_SCOPE_AGENT);
        store_bf16_sc(&Sout[(size_t)b * Hh + hme], sn);
      }
      // ---- publish: drain S/C stores (vmcnt(0) via barrier), bump flag ----
      __syncthreads();
      if (tid == 0) atomicAdd(done + i * Oo + j, 1);
      // ---- out stores AFTER publish (never read in-kernel; overlaps next
      //      cell's poll; drained by the next publish barrier / kernel end) --
#pragma unroll
      for (int ra = 0; ra < 4; ra++)
        out[(((size_t)i * Oo + j) * Bb + (brow + ra)) * Hh + hme] = snv[ra];
    }
  }
}

// ---------------- host ----------------
extern "C" void kernel_launch(void* const* d_in, const int* in_sizes, int n_in,
                              void* d_out, int out_size, void* d_ws, size_t ws_size,
                              hipStream_t stream) {
  const float* x    = (const float*)d_in[0];
  const float* y    = (const float*)d_in[1];
  const float* Wx   = (const float*)d_in[2];
  const float* Ws   = (const float*)d_in[3];
  const float* bias = (const float*)d_in[4];
  float* out = (float*)d_out;

  char* ws = (char*)d_ws;
  size_t off = 0;
  auto alloc = [&](size_t bytes) -> void* {
    void* p = ws + off;
    off += (bytes + 255) & ~(size_t)255;
    return p;
  };
  __hip_bfloat16* Wxp = (__hip_bfloat16*)alloc((size_t)NG * KK * 2);
  __hip_bfloat16* Wsp = (__hip_bfloat16*)alloc((size_t)NG * KK * 2);
  __hip_bfloat16* xb  = (__hip_bfloat16*)alloc((size_t)Ii * Bb * Ff * 2);
  __hip_bfloat16* yb  = (__hip_bfloat16*)alloc((size_t)Oo * Bb * Ff * 2);
  float* Px = (float*)alloc((size_t)Ii * Bb * NG * 4);
  float* Py = (float*)alloc((size_t)Oo * Bb * NG * 4);
  __hip_bfloat16* Sring = (__hip_bfloat16*)alloc((size_t)Ii * RING * Bb * Hh * 2);
  float* Cring = (float*)alloc((size_t)Ii * RING * Bb * Hh * 4);
  char* zbase = ws + off;
  __hip_bfloat16* Szero = (__hip_bfloat16*)alloc((size_t)Bb * Hh * 2);
  int*   done = (int*)alloc((size_t)Ii * Oo * 4);
  size_t zBytes = (size_t)((ws + off) - zbase);

  // only the zero-buffer + flags need zeroing (ring slots are written before
  // any read per the dependency order)
  hipMemsetAsync(zbase, 0, zBytes, stream);

  hipLaunchKernelGGL(pack_kernel, dim3(512), dim3(256), 0, stream,
                     Wx, Ws, x, y, Wxp, Wsp, xb, yb);
  hipLaunchKernelGGL(pregemm, dim3(2 * Ii * HCHUNKS), dim3(256), 0, stream,
                     xb, yb, Wxp, Px, Py);

  void* args[] = {(void*)&Px, (void*)&Py, (void*)&bias, (void*)&Wsp,
                  (void*)&Sring, (void*)&Cring, (void*)&Szero,
                  (void*)&out, (void*)&done};
  hipLaunchCooperativeKernel((void*)lstm_row, dim3(WORKERS * HCHUNKS), dim3(256),
                             args, 0, stream);
}

// Round 8
// 1507.005 us; speedup vs baseline: 1.0907x; 1.0010x over previous
//
#include <hip/hip_runtime.h>
#include <hip/hip_bf16.h>

typedef __attribute__((ext_vector_type(8))) short short8;
typedef __attribute__((ext_vector_type(4))) float floatx4;

#define Bb 64
#define Ii 48
#define Oo 48
#define Ff 256
#define Hh 256
#define NG 1280      // 5*H
#define KK 512       // 2F (Wx rows) == 2H (Ws rows)
#define CHUNK 80     // packed cols per wg = 5 gates x 16 h
#define NH 16        // h-values per chunk
#define HCHUNKS 16   // 1280/80
#define RING 4       // j-ring depth for S/C state
#define WLDS_STRIDE_PRE 264  // 256 + 8 pad (pregemm only)

// ---------------- pack / cast kernel ----------------
// Gate-major packing: packed col p = hc*80 + g*16 + hsub <-> orig col
// g*256 + hc*16 + hsub. MFMA output block t == gate t, output col lane == h-sub,
// so the recurrent kernel consumes its accumulators directly (no LDS transpose).
__global__ __launch_bounds__(256) void pack_kernel(
    const float* __restrict__ Wx, const float* __restrict__ Ws,
    const float* __restrict__ x, const float* __restrict__ y,
    __hip_bfloat16* __restrict__ Wxp, __hip_bfloat16* __restrict__ Wsp,
    __hip_bfloat16* __restrict__ xb, __hip_bfloat16* __restrict__ yb) {
  int idx = blockIdx.x * blockDim.x + threadIdx.x;
  int stride = gridDim.x * blockDim.x;
  int total_w = NG * KK;
  for (int t = idx; t < total_w; t += stride) {
    int np = t / KK, k = t % KK;
    int hcp = np / CHUNK;
    int rem = np - hcp * CHUNK;
    int g = rem >> 4;
    int hsub = rem & 15;
    int orig = g * Hh + hcp * NH + hsub;
    Wxp[t] = __float2bfloat16(Wx[k * NG + orig]);
    Wsp[t] = __float2bfloat16(Ws[k * NG + orig]);
  }
  int total_x = Bb * Ii * Ff;
  for (int t = idx; t < total_x; t += stride) {
    int f = t % Ff; int rest = t / Ff; int b = rest % Bb; int i = rest / Bb;
    xb[(i * Bb + b) * Ff + f] = __float2bfloat16(x[(b * Ii + i) * Ff + f]);
    yb[(i * Bb + b) * Ff + f] = __float2bfloat16(y[(b * Oo + i) * Ff + f]);
  }
}

// ---------------- precompute GEMM: Px[i][b][n'], Py[j][b][n'] (packing-agnostic)
__global__ __launch_bounds__(256) void pregemm(
    const __hip_bfloat16* __restrict__ xb, const __hip_bfloat16* __restrict__ yb,
    const __hip_bfloat16* __restrict__ Wxp,
    float* __restrict__ Px, float* __restrict__ Py) {
  __shared__ __hip_bfloat16 Wl[CHUNK * WLDS_STRIDE_PRE];
  int wg = blockIdx.x;
  int isY = wg >= (Ii * HCHUNKS);
  int w = isY ? wg - Ii * HCHUNKS : wg;
  int mblk = w >> 4;
  int hc = w & 15;
  int n0 = hc * CHUNK;
  int koff = isY ? Ff : 0;
  int tid = threadIdx.x;
  for (int idx = tid; idx < CHUNK * (Ff / 8); idx += 256) {
    int cl = idx >> 5;
    int kb = (idx & 31) << 3;
    *(short8*)&Wl[cl * WLDS_STRIDE_PRE + kb] =
        *(const short8*)&Wxp[(n0 + cl) * KK + koff + kb];
  }
  __syncthreads();
  int wave = tid >> 6, lane = tid & 63;
  int lr = lane & 15, q = lane >> 4;
  const __hip_bfloat16* Arow = (isY ? yb : xb) + ((size_t)mblk * Bb + wave * 16 + lr) * Ff;
  floatx4 acc[5];
#pragma unroll
  for (int t = 0; t < 5; t++) acc[t] = (floatx4){0.f, 0.f, 0.f, 0.f};
#pragma unroll
  for (int ks = 0; ks < Ff / 32; ks++) {
    int k = ks * 32 + q * 8;
    short8 a = *(const short8*)(Arow + k);
#pragma unroll
    for (int t = 0; t < 5; t++) {
      short8 bfr = *(const short8*)&Wl[(t * 16 + lr) * WLDS_STRIDE_PRE + k];
      acc[t] = __builtin_amdgcn_mfma_f32_16x16x32_bf16(a, bfr, acc[t], 0, 0, 0);
    }
  }
  float* Pr = (isY ? Py : Px) + (size_t)mblk * Bb * NG + n0;
#pragma unroll
  for (int t = 0; t < 5; t++)
#pragma unroll
    for (int r = 0; r < 4; r++)
      Pr[(wave * 16 + q * 4 + r) * NG + t * 16 + lr] = acc[t][r];
}

// ---------------- coherence helpers (L2-bypassing, no cache-wide fences) ----
__device__ __forceinline__ void wait16(const int* p) {
  while (__hip_atomic_load(p, __ATOMIC_RELAXED, __HIP_MEMORY_SCOPE_AGENT) < HCHUNKS)
    __builtin_amdgcn_s_sleep(1);
}

// 16B bf16 A-fragment via two 8B agent-scope (L1/L2-bypass) loads
__device__ __forceinline__ short8 load8_sc(const __hip_bfloat16* p) {
  const unsigned long long* q = (const unsigned long long*)p;
  union { unsigned long long u[2]; short8 v; } r;
  r.u[0] = __hip_atomic_load(q,     __ATOMIC_RELAXED, __HIP_MEMORY_SCOPE_AGENT);
  r.u[1] = __hip_atomic_load(q + 1, __ATOMIC_RELAXED, __HIP_MEMORY_SCOPE_AGENT);
  return r.v;
}

__device__ __forceinline__ void store_bf16_sc(__hip_bfloat16* p, float f) {
  union { __hip_bfloat16 b; unsigned short u; } cv;
  cv.b = __float2bfloat16(f);
  __hip_atomic_store((unsigned short*)p, cv.u, __ATOMIC_RELAXED, __HIP_MEMORY_SCOPE_AGENT);
}

// ---------------- row-pipelined recurrent kernel ----------------
// PROVEN per-cell protocol (r0/r3/r6/r7), ownership-generalized: nworkers row-
// workers x 16 hchunks; worker w owns rows w, w+nworkers, ... (nrows of them),
// each processed j=0..47 left-to-right. Per cell, lane-parallel waits:
//   lane0: done[i-1][j]   (vertical data dep: S row above + C above)
//   lane1: done[i][j-1]   (sibling hchunks' S slices of own row)
//   lane2: done[i+1][j-4] (WAR: depth-4 j-ring slot reuse)
// The protocol is row-ownership-agnostic: flags are per-cell and global.
// r8 deltas vs r7:
//   - Wl stored UNPADDED (80 x 512, exactly 80 KiB) with an XOR bank swizzle
//     (byte ^= (row&7)<<4 within each 1024B row; write and read sides match):
//     same 2-way-free bank spread as the old +8 pad, but 2 wgs now fit in the
//     160 KiB LDS -> 24 workers x 16 hchunks = 384 wgs, 2/CU.
//   - 24x2 row ownership cuts the critical path 159 -> 119 cells (x0.75);
//     co-resident wg pairs are at different pipeline phases, so one wg's
//     compute hides the other's sync stall.
// Host picks (24,2,384 wgs) if occupancy query says 2 wgs/CU fit, else the
// r7-proven (16,3,256 wgs) with the identical kernel.
__global__ __launch_bounds__(256) void lstm_row(
    const float* __restrict__ Px, const float* __restrict__ Py,
    const float* __restrict__ bias, const __hip_bfloat16* __restrict__ Wsp,
    __hip_bfloat16* __restrict__ Sring, float* __restrict__ Cring,
    const __hip_bfloat16* __restrict__ Szero,
    float* __restrict__ out, int* __restrict__ done,
    int nworkers, int nrows) {
  __shared__ __hip_bfloat16 Wl[CHUNK * KK];  // 81,920 B unpadded, XOR-swizzled
  char* Wb = (char*)Wl;
  int wg = blockIdx.x;
  int worker = wg >> 4;
  int hc = wg & 15;
  int n0 = hc * CHUNK;
  int h0 = hc * NH;
  int tid = threadIdx.x;
  int wave = tid >> 6, lane = tid & 63;
  int lr = lane & 15, q = lane >> 4;
  const int brow = wave * 16 + q * 4;   // elementwise b-rows: brow..brow+3
  const int hme = h0 + lr;              // this thread's h
  const size_t BH = (size_t)Bb * Hh;

  // persistent Ws slice: 80 packed cols x 512 k, XOR-swizzled within each row
  for (int idx = tid; idx < CHUNK * (KK / 8); idx += 256) {
    int cl = idx >> 6;
    int boff = (idx & 63) << 4;                    // byte offset within row
    *(short8*)(Wb + cl * 1024 + (boff ^ ((cl & 7) << 4))) =
        *(const short8*)&Wsp[(size_t)(n0 + cl) * KK + ((idx & 63) << 3)];
  }
  float bv[5];
#pragma unroll
  for (int g = 0; g < 5; g++) bv[g] = bias[g * Hh + hme];
  const int sw = (lr & 7) << 4;         // read-side XOR (row = t*16+lr; t*16%8==0)

#pragma unroll 1
  for (int rr = 0; rr < nrows; rr++) {
    int i = worker + rr * nworkers;
    // ---- per-row: Px slice -> registers (reused for 48 cells) ----
    float pxv[4][5];
#pragma unroll
    for (int ra = 0; ra < 4; ra++)
#pragma unroll
      for (int g = 0; g < 5; g++)
        pxv[ra][g] = Px[((size_t)i * Bb + (brow + ra)) * NG + n0 + g * 16 + lr];

    float cvreg[4];   // register-carried horizontal C state c(i, j-1)
#pragma unroll
    for (int it = 0; it < 4; it++) cvreg[it] = 0.f;

#pragma unroll 1
    for (int j = 0; j < Oo; j++) {
      // ---- prefetch Py slice (immutable, L2-cacheable) before the waits ----
      const float* PyR = Py + (size_t)j * Bb * NG + n0;
      float pyv[4][5];
#pragma unroll
      for (int ra = 0; ra < 4; ra++)
#pragma unroll
        for (int g = 0; g < 5; g++)
          pyv[ra][g] = PyR[(size_t)(brow + ra) * NG + g * 16 + lr];

      // ---- waits: lanes 0/1/2 of wave 0 poll in parallel, barrier broadcasts
      if (tid < 3) {
        const int* fp = nullptr;
        if (tid == 0) {
          if (i > 0) fp = done + (i - 1) * Oo + j;
        } else if (tid == 1) {
          if (j > 0) fp = done + i * Oo + (j - 1);
        } else {
          if (i + 1 < Ii && j >= RING) fp = done + (i + 1) * Oo + (j - RING);
        }
        if (fp) wait16(fp);
      }
      __syncthreads();   // also covers initial Wl staging (rr==0, j==0)

      // ---- state pointers (depth-4 j-ring) ----
      const __hip_bfloat16* Sv = (i > 0)
          ? Sring + ((size_t)(i - 1) * RING + (j & (RING - 1))) * BH : Szero;
      const __hip_bfloat16* Sh = (j > 0)
          ? Sring + ((size_t)i * RING + ((j - 1) & (RING - 1))) * BH : Szero;
      __hip_bfloat16* Sout = Sring + ((size_t)i * RING + (j & (RING - 1))) * BH;
      float* Cout = Cring + ((size_t)i * RING + (j & (RING - 1))) * BH;

      // ---- A-operand batch prefetch: 16 fragments (32x8B agent loads) in
      //      flight at once -> one LLC latency instead of 16 serial ----
      const __hip_bfloat16* SvR = Sv + (size_t)(wave * 16 + lr) * Hh;
      const __hip_bfloat16* ShR = Sh + (size_t)(wave * 16 + lr) * Hh;
      short8 av[16];
#pragma unroll
      for (int ks = 0; ks < 8; ks++)
        av[ks] = load8_sc(SvR + ks * 32 + q * 8);
#pragma unroll
      for (int ks = 0; ks < 8; ks++)
        av[8 + ks] = load8_sc(ShR + ks * 32 + q * 8);

      // ---- C-above loads issued behind the A-batch; drain under MFMAs ----
      float chv[4];
      if (i > 0) {
        const float* Chp = Cring + ((size_t)(i - 1) * RING + (j & (RING - 1))) * BH;
#pragma unroll
        for (int ra = 0; ra < 4; ra++)
          chv[ra] = __hip_atomic_load(&Chp[(size_t)(brow + ra) * Hh + hme],
                                      __ATOMIC_RELAXED, __HIP_MEMORY_SCOPE_AGENT);
      } else {
#pragma unroll
        for (int ra = 0; ra < 4; ra++) chv[ra] = 0.f;
      }

      // ---- GEMM: (64 x 512) @ (512 x 80) from registers + swizzled LDS B ----
      floatx4 acc[5];
#pragma unroll
      for (int t = 0; t < 5; t++) acc[t] = (floatx4){0.f, 0.f, 0.f, 0.f};
#pragma unroll
      for (int ks = 0; ks < KK / 32; ks++) {
        int boff = ks * 64 + q * 16;    // byte offset within row
#pragma unroll
        for (int t = 0; t < 5; t++) {
          short8 bfr = *(const short8*)(Wb + (t * 16 + lr) * 1024 + (boff ^ sw));
          acc[t] = __builtin_amdgcn_mfma_f32_16x16x32_bf16(av[ks], bfr, acc[t], 0, 0, 0);
        }
      }

      // ---- elementwise LSTM update directly from accumulators ----
      // acc[t][ra] = (gate t, b = brow+ra, h = hme)
      float snv[4];
#pragma unroll
      for (int ra = 0; ra < 4; ra++) {
        int b = brow + ra;
        float pre[5];
#pragma unroll
        for (int g = 0; g < 5; g++)
          pre[g] = acc[g][ra] + pxv[ra][g] + pyv[ra][g] + bv[g];
        float ig = 1.f / (1.f + __expf(-pre[0]));
        float fg = 1.f / (1.f + __expf(-pre[1]));
        float og = 1.f / (1.f + __expf(-pre[2]));
        float lg = 1.f / (1.f + __expf(-pre[3]));
        float gg = 1.f - 2.f / (__expf(2.f * pre[4]) + 1.f);   // tanh
        float cn = fg * (lg * chv[ra] + (1.f - lg) * cvreg[ra]) + ig * gg;
        float tc = 1.f - 2.f / (__expf(2.f * cn) + 1.f);
        float sn = og * tc;
        cvreg[ra] = cn;                      // horizontal C for cell (i, j+1)
        snv[ra] = sn;
        __hip_atomic_store(&Cout[(size_t)b * Hh + hme], cn,
                           __ATOMIC_RELAXED, __HIP_MEMORY_SCOPE_AGENT);
        store_bf16_sc(&Sout[(size_t)b * Hh + hme], sn);
      }
      // ---- publish: drain S/C stores (vmcnt(0) via barrier), bump flag ----
      __syncthreads();
      if (tid == 0) atomicAdd(done + i * Oo + j, 1);
      // ---- out stores AFTER publish (never read in-kernel; overlaps next
      //      cell's poll; drained by the next publish barrier / kernel end) --
#pragma unroll
      for (int ra = 0; ra < 4; ra++)
        out[(((size_t)i * Oo + j) * Bb + (brow + ra)) * Hh + hme] = snv[ra];
    }
  }
}

// ---------------- host ----------------
extern "C" void kernel_launch(void* const* d_in, const int* in_sizes, int n_in,
                              void* d_out, int out_size, void* d_ws, size_t ws_size,
                              hipStream_t stream) {
  const float* x    = (const float*)d_in[0];
  const float* y    = (const float*)d_in[1];
  const float* Wx   = (const float*)d_in[2];
  const float* Ws   = (const float*)d_in[3];
  const float* bias = (const float*)d_in[4];
  float* out = (float*)d_out;

  char* ws = (char*)d_ws;
  size_t off = 0;
  auto alloc = [&](size_t bytes) -> void* {
    void* p = ws + off;
    off += (bytes + 255) & ~(size_t)255;
    return p;
  };
  __hip_bfloat16* Wxp = (__hip_bfloat16*)alloc((size_t)NG * KK * 2);
  __hip_bfloat16* Wsp = (__hip_bfloat16*)alloc((size_t)NG * KK * 2);
  __hip_bfloat16* xb  = (__hip_bfloat16*)alloc((size_t)Ii * Bb * Ff * 2);
  __hip_bfloat16* yb  = (__hip_bfloat16*)alloc((size_t)Oo * Bb * Ff * 2);
  float* Px = (float*)alloc((size_t)Ii * Bb * NG * 4);
  float* Py = (float*)alloc((size_t)Oo * Bb * NG * 4);
  __hip_bfloat16* Sring = (__hip_bfloat16*)alloc((size_t)Ii * RING * Bb * Hh * 2);
  float* Cring = (float*)alloc((size_t)Ii * RING * Bb * Hh * 4);
  char* zbase = ws + off;
  __hip_bfloat16* Szero = (__hip_bfloat16*)alloc((size_t)Bb * Hh * 2);
  int*   done = (int*)alloc((size_t)Ii * Oo * 4);
  size_t zBytes = (size_t)((ws + off) - zbase);

  // only the zero-buffer + flags need zeroing (ring slots are written before
  // any read per the dependency order)
  hipMemsetAsync(zbase, 0, zBytes, stream);

  hipLaunchKernelGGL(pack_kernel, dim3(512), dim3(256), 0, stream,
                     Wx, Ws, x, y, Wxp, Wsp, xb, yb);
  hipLaunchKernelGGL(pregemm, dim3(2 * Ii * HCHUNKS), dim3(256), 0, stream,
                     xb, yb, Wxp, Px, Py);

  // choose 24x2 (384 wgs, needs 2 wgs/CU) if it fits, else proven 16x3.
  // Occupancy query is a pure query -> graph-capture-safe; no failing launch
  // is ever attempted.
  int perCU = 0;
  int nworkers = 16, nrows = 3;
  if (hipOccupancyMaxActiveBlocksPerMultiprocessor(&perCU, lstm_row, 256, 0)
          == hipSuccess && perCU >= 2) {
    nworkers = 24; nrows = 2;
  }
  void* args[] = {(void*)&Px, (void*)&Py, (void*)&bias, (void*)&Wsp,
                  (void*)&Sring, (void*)&Cring, (void*)&Szero,
                  (void*)&out, (void*)&done, (void*)&nworkers, (void*)&nrows};
  hipLaunchCooperativeKernel((void*)lstm_row, dim3(nworkers * HCHUNKS), dim3(256),
                             args, 0, stream);
}